// Round 12
// baseline (208.741 us; speedup 1.0000x reference)
//
#include <hip/hip_runtime.h>
#include <hip/hip_bf16.h>

// CostAttention on MI355X — round 25: prep split 3-ways (diagnostic) +
// attn S-chain split.
// R24 post-mortem: 4-wave/2xTLP attn = 105.4us IDENTICAL to 2-wave R14 ->
// occupancy is not the lever; per-wave MFMA/VALU phase anti-correlation +
// in-iter serial chains suspected. prep (~65-72us, 40% of total) has survived
// 4 theories unmeasured — split into prepK/prepQ/prepV so rocprof times each
// phase directly.
// attn edit (R24 base): each S accumulator was a 6-deep dependent MFMA chain;
// split by c0 into two independent 3-chains + f32x4 add (1-ulp reorder).
//
// ws layout: shorts [Qh][Ql][Kh][Kl][Vh], each SZ = 1,638,400 shorts (16.4MB).
//   Q/K chunk  ((b*400+mi)*2+c0)*512 + lane*8 : elem [r=16mi+l16][c=32c0+8qq+j]
//   V   chunk  (((b*100+i64)*8)+ct*2+mh)*512 + lane*8 : elem [c=16ct+l16][m=64i64+32mh+8qq+j]

#define NPIX 6400
#define SZ 1638400
#define SHIFT2 11.541560327111707f   // 8 * log2(e)

typedef float f32x4 __attribute__((ext_vector_type(4)));
typedef short bf16x8 __attribute__((ext_vector_type(8)));

#if defined(__has_builtin)
#if __has_builtin(__builtin_amdgcn_sched_barrier)
#define SCHED_FENCE() __builtin_amdgcn_sched_barrier(0)
#endif
#if __has_builtin(__builtin_amdgcn_exp2f)
#define EXP2(x) __builtin_amdgcn_exp2f(x)
#endif
#endif
#ifndef SCHED_FENCE
#define SCHED_FENCE()
#endif
#ifndef EXP2
#define EXP2(x) exp2f(x)
#endif

__device__ __forceinline__ void split2(float x, short& h, short& l) {
  unsigned xb = __float_as_uint(x);
  h = (short)(xb >> 16);
  float r = x - __uint_as_float(xb & 0xffff0000u);
  l = (short)(__float_as_uint(r) >> 16);
}

__device__ __forceinline__ short rne_bf16(float x) {
  unsigned u = __float_as_uint(x);
  return (short)((u + 0x7fffu + ((u >> 16) & 1u)) >> 16);
}

__device__ __forceinline__ unsigned pk2(float a, float b) {
  __hip_bfloat162 t = __float22bfloat162_rn(make_float2(a, b));
  unsigned r;
  __builtin_memcpy(&r, &t, 4);
  return r;
}

// ---------------- prepK: K split (trunc hi/lo, 3-term S) — grid 400 ---------
__global__ __launch_bounds__(256, 4) void prepK(
    const float* __restrict__ keys, short* __restrict__ ws)
{
  const int tid = threadIdx.x;
  const int w = tid >> 6;
  const int lane = tid & 63, l16 = lane & 15, qq = lane >> 4;
  short* Kh = ws + 2 * SZ; short* Kl = ws + 3 * SZ;
  const int x = blockIdx.x;

  __shared__ float T[64 * 65];

  const int b = x / 100, t64 = x % 100;
  const int m0 = t64 * 64;
  const float* kb = keys + (size_t)b * 64 * NPIX;
  {
    const int ch = tid >> 2, ml = (tid & 3) * 4;
    const float* src = kb + (size_t)ch * NPIX + m0 + ml;
    #pragma unroll
    for (int u = 0; u < 4; ++u)
      *(float4*)&T[ch * 65 + ml + 16 * u] = *(const float4*)(src + 16 * u);
  }
  __syncthreads();
  const int mi = t64 * 4 + w;
  #pragma unroll
  for (int c0 = 0; c0 < 2; ++c0) {
    float t[8];
    #pragma unroll
    for (int j = 0; j < 8; ++j)
      t[j] = T[(32 * c0 + 8 * qq + j) * 65 + 16 * w + l16];
    bf16x8 h8, l8;
    #pragma unroll
    for (int j = 0; j < 8; ++j) { short h, l; split2(t[j], h, l); h8[j] = h; l8[j] = l; }
    const int off = ((b * 400 + mi) * 2 + c0) * 512 + lane * 8;
    *(bf16x8*)(Kh + off) = h8;
    *(bf16x8*)(Kl + off) = l8;
  }
}

// ---------------- prepQ: projection + trunc hi/lo split — grid 400 ----------
__global__ __launch_bounds__(256, 4) void prepQ(
    const float* __restrict__ query, const float* __restrict__ Wq,
    const float* __restrict__ bq, short* __restrict__ ws)
{
  const int tid = threadIdx.x;
  const int w = tid >> 6;
  const int lane = tid & 63, l16 = lane & 15, qq = lane >> 4;
  short* Qh = ws; short* Ql = ws + SZ;
  const int y = blockIdx.x;

  __shared__ float T[64 * 65];

  const int b = y / 100, t64 = y % 100;
  const int r0 = t64 * 64;
  const float* qb = query + (size_t)b * 64 * NPIX;
  {
    const int ch = tid >> 2, ml = (tid & 3) * 4;
    const float* src = qb + (size_t)ch * NPIX + r0 + ml;
    #pragma unroll
    for (int u = 0; u < 4; ++u)
      *(float4*)&T[ch * 65 + ml + 16 * u] = *(const float4*)(src + 16 * u);
  }
  __syncthreads();

  {
    float xv[64];
    #pragma unroll
    for (int cin = 0; cin < 64; ++cin)
      xv[cin] = T[cin * 65 + lane];
    __syncthreads();   // all xv reads done before T is overwritten

    #pragma unroll 4
    for (int c16 = 0; c16 < 16; ++c16) {
      const int co = __builtin_amdgcn_readfirstlane(16 * w + c16);
      const float* row = Wq + co * 64;
      float a = 0.f;
      #pragma unroll
      for (int cin = 0; cin < 64; ++cin)
        a += row[cin] * xv[cin];
      // scale = (1/8)*log2(e): S in log2 domain -> raw exp2 in main
      T[co * 65 + lane] = (a + bq[co]) * 0.18033688011112042f;
    }
  }
  __syncthreads();

  const int mi = t64 * 4 + w;
  #pragma unroll
  for (int c0 = 0; c0 < 2; ++c0) {
    float t[8];
    #pragma unroll
    for (int j = 0; j < 8; ++j)
      t[j] = T[(32 * c0 + 8 * qq + j) * 65 + 16 * w + l16];
    bf16x8 h8, l8;
    #pragma unroll
    for (int j = 0; j < 8; ++j) { short h, l; split2(t[j], h, l); h8[j] = h; l8[j] = l; }
    const int off = ((b * 400 + mi) * 2 + c0) * 512 + lane * 8;
    *(bf16x8*)(Qh + off) = h8;
    *(bf16x8*)(Ql + off) = l8;
  }
}

// ---------------- prepV: RNE bf16, hi only — grid 200 -----------------------
__global__ __launch_bounds__(256, 4) void prepV(
    const float* __restrict__ values, short* __restrict__ ws)
{
  const int tid = threadIdx.x;
  const int w = tid >> 6;
  const int lane = tid & 63, l16 = lane & 15, qq = lane >> 4;
  short* Vh = ws + 4 * SZ;

  const int gw = blockIdx.x * 4 + w;
  const int b = gw / 200, rest = gw % 200;
  const int i = rest / 2, half = rest % 2;
  const float* vb = values + (size_t)b * 64 * NPIX;
  #pragma unroll
  for (int cc = 0; cc < 2; ++cc) {
    const int ct = 2 * half + cc;
    #pragma unroll
    for (int mh = 0; mh < 2; ++mh) {
      const float* vp = vb + (size_t)(16 * ct + l16) * NPIX + 64 * i + 32 * mh + 8 * qq;
      const float4 a  = *(const float4*)vp;
      const float4 b4 = *(const float4*)(vp + 4);
      const float t[8] = {a.x, a.y, a.z, a.w, b4.x, b4.y, b4.z, b4.w};
      bf16x8 h8;
      #pragma unroll
      for (int j = 0; j < 8; ++j) h8[j] = rne_bf16(t[j]);
      const int off = (((b * 100 + i) * 8) + ct * 2 + mh) * 512 + lane * 8;
      *(bf16x8*)(Vh + off) = h8;
    }
  }
}

// ---------------- main: 800 blocks x 256 thr (4 waves); 32-row jobs ---------
// R24 structure + S-chain split: two independent 3-MFMA chains per acc (by
// c0) + f32x4 add, instead of one 6-deep dependent chain.
__global__ __launch_bounds__(256, 4) void attn_main(
    const short* __restrict__ ws, float* __restrict__ out)
{
  const int tid  = threadIdx.x;
  const int w    = tid >> 6;          // wave 0..3 = m-quarter
  const int lane = tid & 63;
  const int l16  = lane & 15, qq = lane >> 4;
  const int x = blockIdx.x;
  const int b    = x & 3;             // batch -> XCD spread
  const int rj2  = x >> 2;            // 0..199 (32-row job)
  const int rb   = rj2 * 32;

  const short* Qh = ws;
  const short* Kh = ws + 2 * SZ;
  const short* Vh = ws + 4 * SZ;
  float* ob = out + (size_t)b * 64 * NPIX;

  __shared__ char smem[16896];
  short* P   = ((short*)smem) + (w << 10);   // wave-private 1024 shorts
  short* QH  = ((short*)smem) + 4096;        // byte 8192
  short* QL  = ((short*)smem) + 6144;        // byte 12288
  float* OC  = (float*)smem;
  float* LST = (float*)(smem + 16384);       // [4 waves][2 strips][16]

  // stage Q hi+lo frags into LDS (4x redundant across waves, benign)
  {
    const short* qp = Qh + (size_t)((b * 400 + rj2 * 2) * 2) * 512 + lane * 8;
    #pragma unroll
    for (int s = 0; s < 2; ++s)
      #pragma unroll
      for (int c0 = 0; c0 < 2; ++c0) {
        *(bf16x8*)(QH + ((s * 2 + c0) * 64 + lane) * 8) =
            *(const bf16x8*)(qp + (s * 2 + c0) * 512);
        *(bf16x8*)(QL + ((s * 2 + c0) * 64 + lane) * 8) =
            *(const bf16x8*)(qp + SZ + (s * 2 + c0) * 512);
      }
  }
  __syncthreads();

  f32x4 zero4 = {0.f, 0.f, 0.f, 0.f};
  f32x4 oacc[4][2];
  f32x4 lacc[2];
  #pragma unroll
  for (int ct = 0; ct < 4; ++ct)
    #pragma unroll
    for (int s = 0; s < 2; ++s) oacc[ct][s] = zero4;
  #pragma unroll
  for (int s = 0; s < 2; ++s) lacc[s] = zero4;

  bf16x8 onesA;
  #pragma unroll
  for (int j = 0; j < 8; ++j) onesA[j] = (short)0x3F80;

  bf16x8 kfh[2][2], kfl[2][2];
  bf16x8 vfh[4];

  auto loadK = [&](int i2) {
    const short* kp = Kh + (size_t)((b * 400 + 2 * i2) * 2) * 512 + lane * 8;
    #pragma unroll
    for (int mt = 0; mt < 2; ++mt)
      #pragma unroll
      for (int c0 = 0; c0 < 2; ++c0) {
        kfh[mt][c0] = *(const bf16x8*)(kp + (mt * 2 + c0) * 512);
        kfl[mt][c0] = *(const bf16x8*)(kp + SZ + (mt * 2 + c0) * 512);
      }
  };
  auto loadV = [&](int i2) {
    const short* vp = Vh + (size_t)((b * 100 + (i2 >> 1)) * 8) * 512 + lane * 8;
    #pragma unroll
    for (int ct = 0; ct < 4; ++ct)
      vfh[ct] = *(const bf16x8*)(vp + (ct * 2 + (i2 & 1)) * 512);
  };

  // wave w owns m-chunks [50w, 50w+50) of 32 m each
  const int i0 = w * 50;
  loadK(i0);
  loadV(i0);

  for (int it = 0; it < 50; ++it) {
    const int i2 = i0 + it;
    const int inext = (it == 49) ? i0 : i2 + 1;

    // ---- both strips' S-MFMAs: per acc, two independent 3-chains (by c0)
    f32x4 a0[2], a1[2];
    #pragma unroll
    for (int s = 0; s < 2; ++s) {
      const bf16x8 qh0 = *(const bf16x8*)(QH + ((s * 2 + 0) * 64 + lane) * 8);
      const bf16x8 ql0 = *(const bf16x8*)(QL + ((s * 2 + 0) * 64 + lane) * 8);
      const bf16x8 qh1 = *(const bf16x8*)(QH + ((s * 2 + 1) * 64 + lane) * 8);
      const bf16x8 ql1 = *(const bf16x8*)(QL + ((s * 2 + 1) * 64 + lane) * 8);
      f32x4 t0a = zero4, t0b = zero4, t1a = zero4, t1b = zero4;
      t0a = __builtin_amdgcn_mfma_f32_16x16x32_bf16(kfh[0][0], qh0, t0a, 0, 0, 0);
      t0a = __builtin_amdgcn_mfma_f32_16x16x32_bf16(kfh[0][0], ql0, t0a, 0, 0, 0);
      t0a = __builtin_amdgcn_mfma_f32_16x16x32_bf16(kfl[0][0], qh0, t0a, 0, 0, 0);
      t0b = __builtin_amdgcn_mfma_f32_16x16x32_bf16(kfh[0][1], qh1, t0b, 0, 0, 0);
      t0b = __builtin_amdgcn_mfma_f32_16x16x32_bf16(kfh[0][1], ql1, t0b, 0, 0, 0);
      t0b = __builtin_amdgcn_mfma_f32_16x16x32_bf16(kfl[0][1], qh1, t0b, 0, 0, 0);
      t1a = __builtin_amdgcn_mfma_f32_16x16x32_bf16(kfh[1][0], qh0, t1a, 0, 0, 0);
      t1a = __builtin_amdgcn_mfma_f32_16x16x32_bf16(kfh[1][0], ql0, t1a, 0, 0, 0);
      t1a = __builtin_amdgcn_mfma_f32_16x16x32_bf16(kfl[1][0], qh0, t1a, 0, 0, 0);
      t1b = __builtin_amdgcn_mfma_f32_16x16x32_bf16(kfh[1][1], qh1, t1b, 0, 0, 0);
      t1b = __builtin_amdgcn_mfma_f32_16x16x32_bf16(kfh[1][1], ql1, t1b, 0, 0, 0);
      t1b = __builtin_amdgcn_mfma_f32_16x16x32_bf16(kfl[1][1], qh1, t1b, 0, 0, 0);
      a0[s] = t0a + t0b;
      a1[s] = t1a + t1b;
    }

    SCHED_FENCE();
    loadK(inext);
    SCHED_FENCE();

    // ---- softmax: exp2 + packed RNE, P hi-only
    #pragma unroll
    for (int s = 0; s < 2; ++s) {
      float p0 = EXP2(a0[s][0] - SHIFT2), p1 = EXP2(a0[s][1] - SHIFT2);
      float p2 = EXP2(a0[s][2] - SHIFT2), p3 = EXP2(a0[s][3] - SHIFT2);
      float p4 = EXP2(a1[s][0] - SHIFT2), p5 = EXP2(a1[s][1] - SHIFT2);
      float p6 = EXP2(a1[s][2] - SHIFT2), p7 = EXP2(a1[s][3] - SHIFT2);
      union { unsigned u[2]; short4 s4; } ua, ub;
      ua.u[0] = pk2(p0, p1); ua.u[1] = pk2(p2, p3);
      ub.u[0] = pk2(p4, p5); ub.u[1] = pk2(p6, p7);
      const int gbase = (s * 4 + (qq >> 1)) * 16 + l16;
      *(short4*)(P + (gbase * 8 + 4 * (qq & 1))) = ua.s4;
      *(short4*)(P + ((gbase + 32) * 8 + 4 * (qq & 1))) = ub.s4;
    }

    bf16x8 pf[2];
    #pragma unroll
    for (int s = 0; s < 2; ++s)
      pf[s] = *(const bf16x8*)(P + (((s * 4 + qq) * 16 + l16) * 8));

    // ---- O^T += Vh * P^T ; l += 1 * P
    #pragma unroll
    for (int ct = 0; ct < 4; ++ct)
      #pragma unroll
      for (int s = 0; s < 2; ++s)
        oacc[ct][s] = __builtin_amdgcn_mfma_f32_16x16x32_bf16(vfh[ct], pf[s], oacc[ct][s], 0, 0, 0);
    #pragma unroll
    for (int s = 0; s < 2; ++s)
      lacc[s] = __builtin_amdgcn_mfma_f32_16x16x32_bf16(onesA, pf[s], lacc[s], 0, 0, 0);

    SCHED_FENCE();
    loadV(inext);
    SCHED_FENCE();
  }

  // ---------------- in-block combine across the 4 m-quarters ----------------
  if (qq == 0) {
    #pragma unroll
    for (int s = 0; s < 2; ++s) LST[w * 32 + s * 16 + l16] = lacc[s][0];
  }
  __syncthreads();    // loop done; P/QH region free for OC

  #pragma unroll
  for (int wp = 0; wp < 4; ++wp) {
    if (w == wp) {
      #pragma unroll
      for (int ct = 0; ct < 4; ++ct)
        #pragma unroll
        for (int s = 0; s < 2; ++s)
          #pragma unroll
          for (int r = 0; r < 4; ++r) {
            const int c = 16 * ct + 4 * qq + r;
            const int idx = c * 33 + 16 * s + l16;
            if (wp == 0) OC[idx] = oacc[ct][s][r];
            else         OC[idx] += oacc[ct][s][r];
          }
    }
    __syncthreads();
  }

  // final scale + coalesced store: 256 threads, 8 channels each (32 rows)
  {
    const int r  = tid & 31;
    const int cg = tid >> 5;          // 0..7
    float lsum = 0.f;
    #pragma unroll
    for (int w2 = 0; w2 < 4; ++w2)
      lsum += LST[w2 * 32 + (r >> 4) * 16 + (r & 15)];
    const float inv = 1.0f / lsum;
    #pragma unroll
    for (int u = 0; u < 8; ++u) {
      const int c = cg * 8 + u;
      ob[(size_t)c * NPIX + rb + r] = OC[c * 33 + r] * inv;
    }
  }
}

extern "C" void kernel_launch(void* const* d_in, const int* in_sizes, int n_in,
                              void* d_out, int out_size, void* d_ws, size_t ws_size,
                              hipStream_t stream) {
  const float* query  = (const float*)d_in[0];
  const float* keys   = (const float*)d_in[1];
  const float* values = (const float*)d_in[2];
  const float* Wq     = (const float*)d_in[3];
  const float* bq     = (const float*)d_in[4];
  short* ws = (short*)d_ws;           // 5*SZ*2 = 16.4 MB
  prepK<<<dim3(400), dim3(256), 0, stream>>>(keys, ws);
  prepQ<<<dim3(400), dim3(256), 0, stream>>>(query, Wq, bq, ws);
  prepV<<<dim3(200), dim3(256), 0, stream>>>(values, ws);
  attn_main<<<dim3(800), dim3(256), 0, stream>>>(ws, (float*)d_out);
}

// Round 13
// 203.293 us; speedup vs baseline: 1.0268x; 1.0268x over previous
//
#include <hip/hip_runtime.h>
#include <hip/hip_bf16.h>

// CostAttention on MI355X — round 26: attn revert (R24-exact) + DOUBLE-PREP
// diagnostic. R25 post-mortem: S-chain split spilled under the 64-VGPR alloc
// ((256,4)): WRITE_SIZE 6400->15200KB, attn 105->135us. Reverted.
// prep split was free (2 extra launches ~ 0) but preps still unmeasured
// (~74us inferred, never in top-5). This round launches each prep TWICE
// (pure/idempotent writes; attn still ordered after) -> total delta vs 180us
// single-run config == exact combined prep execution time:
//   ~250us total => preps real (attack prep structurally next);
//   <=190us total => preps cheap, 72us is harness/graph overhead (attack attn
//   or node count next).
//
// ws layout: shorts [Qh][Ql][Kh][Kl][Vh], each SZ = 1,638,400 shorts (16.4MB).
//   Q/K chunk  ((b*400+mi)*2+c0)*512 + lane*8 : elem [r=16mi+l16][c=32c0+8qq+j]
//   V   chunk  (((b*100+i64)*8)+ct*2+mh)*512 + lane*8 : elem [c=16ct+l16][m=64i64+32mh+8qq+j]

#define NPIX 6400
#define SZ 1638400
#define SHIFT2 11.541560327111707f   // 8 * log2(e)

typedef float f32x4 __attribute__((ext_vector_type(4)));
typedef short bf16x8 __attribute__((ext_vector_type(8)));

#if defined(__has_builtin)
#if __has_builtin(__builtin_amdgcn_sched_barrier)
#define SCHED_FENCE() __builtin_amdgcn_sched_barrier(0)
#endif
#if __has_builtin(__builtin_amdgcn_exp2f)
#define EXP2(x) __builtin_amdgcn_exp2f(x)
#endif
#endif
#ifndef SCHED_FENCE
#define SCHED_FENCE()
#endif
#ifndef EXP2
#define EXP2(x) exp2f(x)
#endif

__device__ __forceinline__ void split2(float x, short& h, short& l) {
  unsigned xb = __float_as_uint(x);
  h = (short)(xb >> 16);
  float r = x - __uint_as_float(xb & 0xffff0000u);
  l = (short)(__float_as_uint(r) >> 16);
}

__device__ __forceinline__ short rne_bf16(float x) {
  unsigned u = __float_as_uint(x);
  return (short)((u + 0x7fffu + ((u >> 16) & 1u)) >> 16);
}

__device__ __forceinline__ unsigned pk2(float a, float b) {
  __hip_bfloat162 t = __float22bfloat162_rn(make_float2(a, b));
  unsigned r;
  __builtin_memcpy(&r, &t, 4);
  return r;
}

// ---------------- prepK: K split (trunc hi/lo, 3-term S) — grid 400 ---------
__global__ __launch_bounds__(256, 4) void prepK(
    const float* __restrict__ keys, short* __restrict__ ws)
{
  const int tid = threadIdx.x;
  const int w = tid >> 6;
  const int lane = tid & 63, l16 = lane & 15, qq = lane >> 4;
  short* Kh = ws + 2 * SZ; short* Kl = ws + 3 * SZ;
  const int x = blockIdx.x;

  __shared__ float T[64 * 65];

  const int b = x / 100, t64 = x % 100;
  const int m0 = t64 * 64;
  const float* kb = keys + (size_t)b * 64 * NPIX;
  {
    const int ch = tid >> 2, ml = (tid & 3) * 4;
    const float* src = kb + (size_t)ch * NPIX + m0 + ml;
    #pragma unroll
    for (int u = 0; u < 4; ++u)
      *(float4*)&T[ch * 65 + ml + 16 * u] = *(const float4*)(src + 16 * u);
  }
  __syncthreads();
  const int mi = t64 * 4 + w;
  #pragma unroll
  for (int c0 = 0; c0 < 2; ++c0) {
    float t[8];
    #pragma unroll
    for (int j = 0; j < 8; ++j)
      t[j] = T[(32 * c0 + 8 * qq + j) * 65 + 16 * w + l16];
    bf16x8 h8, l8;
    #pragma unroll
    for (int j = 0; j < 8; ++j) { short h, l; split2(t[j], h, l); h8[j] = h; l8[j] = l; }
    const int off = ((b * 400 + mi) * 2 + c0) * 512 + lane * 8;
    *(bf16x8*)(Kh + off) = h8;
    *(bf16x8*)(Kl + off) = l8;
  }
}

// ---------------- prepQ: projection + trunc hi/lo split — grid 400 ----------
__global__ __launch_bounds__(256, 4) void prepQ(
    const float* __restrict__ query, const float* __restrict__ Wq,
    const float* __restrict__ bq, short* __restrict__ ws)
{
  const int tid = threadIdx.x;
  const int w = tid >> 6;
  const int lane = tid & 63, l16 = lane & 15, qq = lane >> 4;
  short* Qh = ws; short* Ql = ws + SZ;
  const int y = blockIdx.x;

  __shared__ float T[64 * 65];

  const int b = y / 100, t64 = y % 100;
  const int r0 = t64 * 64;
  const float* qb = query + (size_t)b * 64 * NPIX;
  {
    const int ch = tid >> 2, ml = (tid & 3) * 4;
    const float* src = qb + (size_t)ch * NPIX + r0 + ml;
    #pragma unroll
    for (int u = 0; u < 4; ++u)
      *(float4*)&T[ch * 65 + ml + 16 * u] = *(const float4*)(src + 16 * u);
  }
  __syncthreads();

  {
    float xv[64];
    #pragma unroll
    for (int cin = 0; cin < 64; ++cin)
      xv[cin] = T[cin * 65 + lane];
    __syncthreads();   // all xv reads done before T is overwritten

    #pragma unroll 4
    for (int c16 = 0; c16 < 16; ++c16) {
      const int co = __builtin_amdgcn_readfirstlane(16 * w + c16);
      const float* row = Wq + co * 64;
      float a = 0.f;
      #pragma unroll
      for (int cin = 0; cin < 64; ++cin)
        a += row[cin] * xv[cin];
      // scale = (1/8)*log2(e): S in log2 domain -> raw exp2 in main
      T[co * 65 + lane] = (a + bq[co]) * 0.18033688011112042f;
    }
  }
  __syncthreads();

  const int mi = t64 * 4 + w;
  #pragma unroll
  for (int c0 = 0; c0 < 2; ++c0) {
    float t[8];
    #pragma unroll
    for (int j = 0; j < 8; ++j)
      t[j] = T[(32 * c0 + 8 * qq + j) * 65 + 16 * w + l16];
    bf16x8 h8, l8;
    #pragma unroll
    for (int j = 0; j < 8; ++j) { short h, l; split2(t[j], h, l); h8[j] = h; l8[j] = l; }
    const int off = ((b * 400 + mi) * 2 + c0) * 512 + lane * 8;
    *(bf16x8*)(Qh + off) = h8;
    *(bf16x8*)(Ql + off) = l8;
  }
}

// ---------------- prepV: RNE bf16, hi only — grid 200 -----------------------
__global__ __launch_bounds__(256, 4) void prepV(
    const float* __restrict__ values, short* __restrict__ ws)
{
  const int tid = threadIdx.x;
  const int w = tid >> 6;
  const int lane = tid & 63, l16 = lane & 15, qq = lane >> 4;
  short* Vh = ws + 4 * SZ;

  const int gw = blockIdx.x * 4 + w;
  const int b = gw / 200, rest = gw % 200;
  const int i = rest / 2, half = rest % 2;
  const float* vb = values + (size_t)b * 64 * NPIX;
  #pragma unroll
  for (int cc = 0; cc < 2; ++cc) {
    const int ct = 2 * half + cc;
    #pragma unroll
    for (int mh = 0; mh < 2; ++mh) {
      const float* vp = vb + (size_t)(16 * ct + l16) * NPIX + 64 * i + 32 * mh + 8 * qq;
      const float4 a  = *(const float4*)vp;
      const float4 b4 = *(const float4*)(vp + 4);
      const float t[8] = {a.x, a.y, a.z, a.w, b4.x, b4.y, b4.z, b4.w};
      bf16x8 h8;
      #pragma unroll
      for (int j = 0; j < 8; ++j) h8[j] = rne_bf16(t[j]);
      const int off = (((b * 100 + i) * 8) + ct * 2 + mh) * 512 + lane * 8;
      *(bf16x8*)(Vh + off) = h8;
    }
  }
}

// ---------------- main: 800 blocks x 256 thr (4 waves); 32-row jobs ---------
// R24-exact (105.4us known-good): 6-deep S chains, Q hi+lo from LDS.
__global__ __launch_bounds__(256, 4) void attn_main(
    const short* __restrict__ ws, float* __restrict__ out)
{
  const int tid  = threadIdx.x;
  const int w    = tid >> 6;          // wave 0..3 = m-quarter
  const int lane = tid & 63;
  const int l16  = lane & 15, qq = lane >> 4;
  const int x = blockIdx.x;
  const int b    = x & 3;             // batch -> XCD spread
  const int rj2  = x >> 2;            // 0..199 (32-row job)
  const int rb   = rj2 * 32;

  const short* Qh = ws;
  const short* Kh = ws + 2 * SZ;
  const short* Vh = ws + 4 * SZ;
  float* ob = out + (size_t)b * 64 * NPIX;

  __shared__ char smem[16896];
  short* P   = ((short*)smem) + (w << 10);   // wave-private 1024 shorts
  short* QH  = ((short*)smem) + 4096;        // byte 8192
  short* QL  = ((short*)smem) + 6144;        // byte 12288
  float* OC  = (float*)smem;
  float* LST = (float*)(smem + 16384);       // [4 waves][2 strips][16]

  // stage Q hi+lo frags into LDS (4x redundant across waves, benign)
  {
    const short* qp = Qh + (size_t)((b * 400 + rj2 * 2) * 2) * 512 + lane * 8;
    #pragma unroll
    for (int s = 0; s < 2; ++s)
      #pragma unroll
      for (int c0 = 0; c0 < 2; ++c0) {
        *(bf16x8*)(QH + ((s * 2 + c0) * 64 + lane) * 8) =
            *(const bf16x8*)(qp + (s * 2 + c0) * 512);
        *(bf16x8*)(QL + ((s * 2 + c0) * 64 + lane) * 8) =
            *(const bf16x8*)(qp + SZ + (s * 2 + c0) * 512);
      }
  }
  __syncthreads();

  f32x4 zero4 = {0.f, 0.f, 0.f, 0.f};
  f32x4 oacc[4][2];
  f32x4 lacc[2];
  #pragma unroll
  for (int ct = 0; ct < 4; ++ct)
    #pragma unroll
    for (int s = 0; s < 2; ++s) oacc[ct][s] = zero4;
  #pragma unroll
  for (int s = 0; s < 2; ++s) lacc[s] = zero4;

  bf16x8 onesA;
  #pragma unroll
  for (int j = 0; j < 8; ++j) onesA[j] = (short)0x3F80;

  bf16x8 kfh[2][2], kfl[2][2];
  bf16x8 vfh[4];

  auto loadK = [&](int i2) {
    const short* kp = Kh + (size_t)((b * 400 + 2 * i2) * 2) * 512 + lane * 8;
    #pragma unroll
    for (int mt = 0; mt < 2; ++mt)
      #pragma unroll
      for (int c0 = 0; c0 < 2; ++c0) {
        kfh[mt][c0] = *(const bf16x8*)(kp + (mt * 2 + c0) * 512);
        kfl[mt][c0] = *(const bf16x8*)(kp + SZ + (mt * 2 + c0) * 512);
      }
  };
  auto loadV = [&](int i2) {
    const short* vp = Vh + (size_t)((b * 100 + (i2 >> 1)) * 8) * 512 + lane * 8;
    #pragma unroll
    for (int ct = 0; ct < 4; ++ct)
      vfh[ct] = *(const bf16x8*)(vp + (ct * 2 + (i2 & 1)) * 512);
  };

  // wave w owns m-chunks [50w, 50w+50) of 32 m each
  const int i0 = w * 50;
  loadK(i0);
  loadV(i0);

  for (int it = 0; it < 50; ++it) {
    const int i2 = i0 + it;
    const int inext = (it == 49) ? i0 : i2 + 1;

    // ---- both strips' S-MFMAs (4 independent chains), Q from LDS
    f32x4 a0[2], a1[2];
    #pragma unroll
    for (int s = 0; s < 2; ++s) {
      f32x4 t0 = zero4, t1 = zero4;
      #pragma unroll
      for (int c0 = 0; c0 < 2; ++c0) {
        const bf16x8 qh = *(const bf16x8*)(QH + ((s * 2 + c0) * 64 + lane) * 8);
        const bf16x8 ql = *(const bf16x8*)(QL + ((s * 2 + c0) * 64 + lane) * 8);
        t0 = __builtin_amdgcn_mfma_f32_16x16x32_bf16(kfh[0][c0], qh, t0, 0, 0, 0);
        t0 = __builtin_amdgcn_mfma_f32_16x16x32_bf16(kfh[0][c0], ql, t0, 0, 0, 0);
        t0 = __builtin_amdgcn_mfma_f32_16x16x32_bf16(kfl[0][c0], qh, t0, 0, 0, 0);
        t1 = __builtin_amdgcn_mfma_f32_16x16x32_bf16(kfh[1][c0], qh, t1, 0, 0, 0);
        t1 = __builtin_amdgcn_mfma_f32_16x16x32_bf16(kfh[1][c0], ql, t1, 0, 0, 0);
        t1 = __builtin_amdgcn_mfma_f32_16x16x32_bf16(kfl[1][c0], qh, t1, 0, 0, 0);
      }
      a0[s] = t0; a1[s] = t1;
    }

    SCHED_FENCE();
    loadK(inext);
    SCHED_FENCE();

    // ---- softmax: exp2 + packed RNE, P hi-only
    #pragma unroll
    for (int s = 0; s < 2; ++s) {
      float p0 = EXP2(a0[s][0] - SHIFT2), p1 = EXP2(a0[s][1] - SHIFT2);
      float p2 = EXP2(a0[s][2] - SHIFT2), p3 = EXP2(a0[s][3] - SHIFT2);
      float p4 = EXP2(a1[s][0] - SHIFT2), p5 = EXP2(a1[s][1] - SHIFT2);
      float p6 = EXP2(a1[s][2] - SHIFT2), p7 = EXP2(a1[s][3] - SHIFT2);
      union { unsigned u[2]; short4 s4; } ua, ub;
      ua.u[0] = pk2(p0, p1); ua.u[1] = pk2(p2, p3);
      ub.u[0] = pk2(p4, p5); ub.u[1] = pk2(p6, p7);
      const int gbase = (s * 4 + (qq >> 1)) * 16 + l16;
      *(short4*)(P + (gbase * 8 + 4 * (qq & 1))) = ua.s4;
      *(short4*)(P + ((gbase + 32) * 8 + 4 * (qq & 1))) = ub.s4;
    }

    bf16x8 pf[2];
    #pragma unroll
    for (int s = 0; s < 2; ++s)
      pf[s] = *(const bf16x8*)(P + (((s * 4 + qq) * 16 + l16) * 8));

    // ---- O^T += Vh * P^T ; l += 1 * P
    #pragma unroll
    for (int ct = 0; ct < 4; ++ct)
      #pragma unroll
      for (int s = 0; s < 2; ++s)
        oacc[ct][s] = __builtin_amdgcn_mfma_f32_16x16x32_bf16(vfh[ct], pf[s], oacc[ct][s], 0, 0, 0);
    #pragma unroll
    for (int s = 0; s < 2; ++s)
      lacc[s] = __builtin_amdgcn_mfma_f32_16x16x32_bf16(onesA, pf[s], lacc[s], 0, 0, 0);

    SCHED_FENCE();
    loadV(inext);
    SCHED_FENCE();
  }

  // ---------------- in-block combine across the 4 m-quarters ----------------
  if (qq == 0) {
    #pragma unroll
    for (int s = 0; s < 2; ++s) LST[w * 32 + s * 16 + l16] = lacc[s][0];
  }
  __syncthreads();    // loop done; P/QH region free for OC

  #pragma unroll
  for (int wp = 0; wp < 4; ++wp) {
    if (w == wp) {
      #pragma unroll
      for (int ct = 0; ct < 4; ++ct)
        #pragma unroll
        for (int s = 0; s < 2; ++s)
          #pragma unroll
          for (int r = 0; r < 4; ++r) {
            const int c = 16 * ct + 4 * qq + r;
            const int idx = c * 33 + 16 * s + l16;
            if (wp == 0) OC[idx] = oacc[ct][s][r];
            else         OC[idx] += oacc[ct][s][r];
          }
    }
    __syncthreads();
  }

  // final scale + coalesced store: 256 threads, 8 channels each (32 rows)
  {
    const int r  = tid & 31;
    const int cg = tid >> 5;          // 0..7
    float lsum = 0.f;
    #pragma unroll
    for (int w2 = 0; w2 < 4; ++w2)
      lsum += LST[w2 * 32 + (r >> 4) * 16 + (r & 15)];
    const float inv = 1.0f / lsum;
    #pragma unroll
    for (int u = 0; u < 8; ++u) {
      const int c = cg * 8 + u;
      ob[(size_t)c * NPIX + rb + r] = OC[c * 33 + r] * inv;
    }
  }
}

extern "C" void kernel_launch(void* const* d_in, const int* in_sizes, int n_in,
                              void* d_out, int out_size, void* d_ws, size_t ws_size,
                              hipStream_t stream) {
  const float* query  = (const float*)d_in[0];
  const float* keys   = (const float*)d_in[1];
  const float* values = (const float*)d_in[2];
  const float* Wq     = (const float*)d_in[3];
  const float* bq     = (const float*)d_in[4];
  short* ws = (short*)d_ws;           // 5*SZ*2 = 16.4 MB
  // DIAGNOSTIC: each prep launched twice (idempotent). Total delta vs the
  // single-run config (180.0us, R24 bench) == exact prep execution time.
  prepK<<<dim3(400), dim3(256), 0, stream>>>(keys, ws);
  prepK<<<dim3(400), dim3(256), 0, stream>>>(keys, ws);
  prepQ<<<dim3(400), dim3(256), 0, stream>>>(query, Wq, bq, ws);
  prepQ<<<dim3(400), dim3(256), 0, stream>>>(query, Wq, bq, ws);
  prepV<<<dim3(200), dim3(256), 0, stream>>>(values, ws);
  prepV<<<dim3(200), dim3(256), 0, stream>>>(values, ws);
  attn_main<<<dim3(800), dim3(256), 0, stream>>>(ws, (float*)d_out);
}

// Round 14
// 185.565 us; speedup vs baseline: 1.1249x; 1.0955x over previous
//
#include <hip/hip_runtime.h>
#include <hip/hip_bf16.h>

// CostAttention on MI355X — round 27: Q hi+lo in registers (4-wave attn).
// R26 DECOMPOSITION (double-prep diagnostic): preps = 23.3us total, attn =
// 105.4, FIXED overhead ~49us (constant across 2/4/7 launches — harness/graph,
// not addressable). The 5 prep theories chased overhead that wasn't prep's.
// attn pipe-sums per CU: MFMA 43 + VALU 39 + LDS 37 + VMEM 13 = 132us at only
// 1.26x overlap -> 105. 8 of 14 ds-ops/iter are loop-invariant QH/QL reads.
// This round: QH/QL -> VGPRs on R24 structure; launch_bounds (256,2) so the
// allocator can exceed 64 VGPR without spilling (R25's failure); LDS 9216B.
// Launcher: combined prep (R22, best measured). All compute bit-identical.
// Tripwire: WRITE_SIZE must stay 6400KB (spill); revert on regression.
//
// ws layout: shorts [Qh][Ql][Kh][Kl][Vh], each SZ = 1,638,400 shorts (16.4MB).
//   Q/K chunk  ((b*400+mi)*2+c0)*512 + lane*8 : elem [r=16mi+l16][c=32c0+8qq+j]
//   V   chunk  (((b*100+i64)*8)+ct*2+mh)*512 + lane*8 : elem [c=16ct+l16][m=64i64+32mh+8qq+j]

#define NPIX 6400
#define SZ 1638400
#define SHIFT2 11.541560327111707f   // 8 * log2(e)

typedef float f32x4 __attribute__((ext_vector_type(4)));
typedef short bf16x8 __attribute__((ext_vector_type(8)));

#if defined(__has_builtin)
#if __has_builtin(__builtin_amdgcn_sched_barrier)
#define SCHED_FENCE() __builtin_amdgcn_sched_barrier(0)
#endif
#if __has_builtin(__builtin_amdgcn_exp2f)
#define EXP2(x) __builtin_amdgcn_exp2f(x)
#endif
#endif
#ifndef SCHED_FENCE
#define SCHED_FENCE()
#endif
#ifndef EXP2
#define EXP2(x) exp2f(x)
#endif

__device__ __forceinline__ void split2(float x, short& h, short& l) {
  unsigned xb = __float_as_uint(x);
  h = (short)(xb >> 16);
  float r = x - __uint_as_float(xb & 0xffff0000u);
  l = (short)(__float_as_uint(r) >> 16);
}

__device__ __forceinline__ short rne_bf16(float x) {
  unsigned u = __float_as_uint(x);
  return (short)((u + 0x7fffu + ((u >> 16) & 1u)) >> 16);
}

__device__ __forceinline__ unsigned pk2(float a, float b) {
  __hip_bfloat162 t = __float22bfloat162_rn(make_float2(a, b));
  unsigned r;
  __builtin_memcpy(&r, &t, 4);
  return r;
}

// ---------------- prep (combined, R22 version — best measured) --------------
// grid 1000: [0,400) K (b,m-tile) | [400,800) Q-proj (b,r-tile) | [800,1000) V
__global__ __launch_bounds__(256, 4) void prep(
    const float* __restrict__ query, const float* __restrict__ keys,
    const float* __restrict__ values, const float* __restrict__ Wq,
    const float* __restrict__ bq, short* __restrict__ ws)
{
  const int tid = threadIdx.x;
  const int w = tid >> 6;
  const int lane = tid & 63, l16 = lane & 15, qq = lane >> 4;
  short* Qh = ws;          short* Ql = ws + SZ;
  short* Kh = ws + 2 * SZ; short* Kl = ws + 3 * SZ;
  short* Vh = ws + 4 * SZ;
  const int x = blockIdx.x;

  __shared__ float T[64 * 65];   // 16.6 KB; Q phase reuses it for outputs

  if (x < 400) {                      // ---- K split (trunc hi/lo, 3-term S)
    const int b = x / 100, t64 = x % 100;
    const int m0 = t64 * 64;
    const float* kb = keys + (size_t)b * 64 * NPIX;
    {
      const int ch = tid >> 2, ml = (tid & 3) * 4;
      const float* src = kb + (size_t)ch * NPIX + m0 + ml;
      #pragma unroll
      for (int u = 0; u < 4; ++u)
        *(float4*)&T[ch * 65 + ml + 16 * u] = *(const float4*)(src + 16 * u);
    }
    __syncthreads();
    const int mi = t64 * 4 + w;
    #pragma unroll
    for (int c0 = 0; c0 < 2; ++c0) {
      float t[8];
      #pragma unroll
      for (int j = 0; j < 8; ++j)
        t[j] = T[(32 * c0 + 8 * qq + j) * 65 + 16 * w + l16];
      bf16x8 h8, l8;
      #pragma unroll
      for (int j = 0; j < 8; ++j) { short h, l; split2(t[j], h, l); h8[j] = h; l8[j] = l; }
      const int off = ((b * 400 + mi) * 2 + c0) * 512 + lane * 8;
      *(bf16x8*)(Kh + off) = h8;
      *(bf16x8*)(Kl + off) = l8;
    }
  } else if (x < 800) {               // ---- Q projection + trunc hi/lo split
    const int y = x - 400;
    const int b = y / 100, t64 = y % 100;
    const int r0 = t64 * 64;
    const float* qb = query + (size_t)b * 64 * NPIX;
    {
      const int ch = tid >> 2, ml = (tid & 3) * 4;
      const float* src = qb + (size_t)ch * NPIX + r0 + ml;
      #pragma unroll
      for (int u = 0; u < 4; ++u)
        *(float4*)&T[ch * 65 + ml + 16 * u] = *(const float4*)(src + 16 * u);
    }
    __syncthreads();

    {
      float xv[64];
      #pragma unroll
      for (int cin = 0; cin < 64; ++cin)
        xv[cin] = T[cin * 65 + lane];
      __syncthreads();   // all xv reads done before T is overwritten

      #pragma unroll 4
      for (int c16 = 0; c16 < 16; ++c16) {
        const int co = __builtin_amdgcn_readfirstlane(16 * w + c16);
        const float* row = Wq + co * 64;
        float a = 0.f;
        #pragma unroll
        for (int cin = 0; cin < 64; ++cin)
          a += row[cin] * xv[cin];
        // scale = (1/8)*log2(e): S in log2 domain -> raw exp2 in main
        T[co * 65 + lane] = (a + bq[co]) * 0.18033688011112042f;
      }
    }
    __syncthreads();

    const int mi = t64 * 4 + w;
    #pragma unroll
    for (int c0 = 0; c0 < 2; ++c0) {
      float t[8];
      #pragma unroll
      for (int j = 0; j < 8; ++j)
        t[j] = T[(32 * c0 + 8 * qq + j) * 65 + 16 * w + l16];
      bf16x8 h8, l8;
      #pragma unroll
      for (int j = 0; j < 8; ++j) { short h, l; split2(t[j], h, l); h8[j] = h; l8[j] = l; }
      const int off = ((b * 400 + mi) * 2 + c0) * 512 + lane * 8;
      *(bf16x8*)(Qh + off) = h8;
      *(bf16x8*)(Ql + off) = l8;
    }
  } else {                            // ---- V: RNE bf16, hi only
    const int gw = (x - 800) * 4 + w;
    const int b = gw / 200, rest = gw % 200;
    const int i = rest / 2, half = rest % 2;
    const float* vb = values + (size_t)b * 64 * NPIX;
    #pragma unroll
    for (int cc = 0; cc < 2; ++cc) {
      const int ct = 2 * half + cc;
      #pragma unroll
      for (int mh = 0; mh < 2; ++mh) {
        const float* vp = vb + (size_t)(16 * ct + l16) * NPIX + 64 * i + 32 * mh + 8 * qq;
        const float4 a  = *(const float4*)vp;
        const float4 b4 = *(const float4*)(vp + 4);
        const float t[8] = {a.x, a.y, a.z, a.w, b4.x, b4.y, b4.z, b4.w};
        bf16x8 h8;
        #pragma unroll
        for (int j = 0; j < 8; ++j) h8[j] = rne_bf16(t[j]);
        const int off = (((b * 100 + i) * 8) + ct * 2 + mh) * 512 + lane * 8;
        *(bf16x8*)(Vh + off) = h8;
      }
    }
  }
}

// ---------------- main: 800 blocks x 256 thr (4 waves); 32-row jobs ---------
// R24 structure, but Q hi+lo in REGISTERS (removes 8 loop-invariant ds_reads
// per iter). (256,2): VGPR cap relaxed so no spill (R25 lesson).
// LDS (bytes): P 4x2048=8192 @0 | OC [64][33] f32 = 8448 aliases @0 after
// loop | LST [4][32] f32 = 512 @8448 -> smem 9216.
__global__ __launch_bounds__(256, 2) void attn_main(
    const short* __restrict__ ws, float* __restrict__ out)
{
  const int tid  = threadIdx.x;
  const int w    = tid >> 6;          // wave 0..3 = m-quarter
  const int lane = tid & 63;
  const int l16  = lane & 15, qq = lane >> 4;
  const int x = blockIdx.x;
  const int b    = x & 3;             // batch -> XCD spread
  const int rj2  = x >> 2;            // 0..199 (32-row job)
  const int rb   = rj2 * 32;

  const short* Qh = ws;
  const short* Kh = ws + 2 * SZ;
  const short* Vh = ws + 4 * SZ;
  float* ob = out + (size_t)b * 64 * NPIX;

  __shared__ char smem[9216];
  short* P   = ((short*)smem) + (w << 10);   // wave-private 1024 shorts
  float* OC  = (float*)smem;                 // combine phase (aliases P)
  float* LST = (float*)(smem + 8448);        // [4 waves][2 strips][16]

  // ---- Q hi+lo frags in registers (loop-invariant; same bytes the old LDS
  // staging delivered to this lane)
  bf16x8 qfh[2][2], qfl[2][2];
  {
    const short* qp = Qh + (size_t)((b * 400 + rj2 * 2) * 2) * 512 + lane * 8;
    #pragma unroll
    for (int s = 0; s < 2; ++s)
      #pragma unroll
      for (int c0 = 0; c0 < 2; ++c0) {
        qfh[s][c0] = *(const bf16x8*)(qp + (s * 2 + c0) * 512);
        qfl[s][c0] = *(const bf16x8*)(qp + SZ + (s * 2 + c0) * 512);
      }
  }

  f32x4 zero4 = {0.f, 0.f, 0.f, 0.f};
  f32x4 oacc[4][2];
  f32x4 lacc[2];
  #pragma unroll
  for (int ct = 0; ct < 4; ++ct)
    #pragma unroll
    for (int s = 0; s < 2; ++s) oacc[ct][s] = zero4;
  #pragma unroll
  for (int s = 0; s < 2; ++s) lacc[s] = zero4;

  bf16x8 onesA;
  #pragma unroll
  for (int j = 0; j < 8; ++j) onesA[j] = (short)0x3F80;

  bf16x8 kfh[2][2], kfl[2][2];
  bf16x8 vfh[4];

  auto loadK = [&](int i2) {
    const short* kp = Kh + (size_t)((b * 400 + 2 * i2) * 2) * 512 + lane * 8;
    #pragma unroll
    for (int mt = 0; mt < 2; ++mt)
      #pragma unroll
      for (int c0 = 0; c0 < 2; ++c0) {
        kfh[mt][c0] = *(const bf16x8*)(kp + (mt * 2 + c0) * 512);
        kfl[mt][c0] = *(const bf16x8*)(kp + SZ + (mt * 2 + c0) * 512);
      }
  };
  auto loadV = [&](int i2) {
    const short* vp = Vh + (size_t)((b * 100 + (i2 >> 1)) * 8) * 512 + lane * 8;
    #pragma unroll
    for (int ct = 0; ct < 4; ++ct)
      vfh[ct] = *(const bf16x8*)(vp + (ct * 2 + (i2 & 1)) * 512);
  };

  // wave w owns m-chunks [50w, 50w+50) of 32 m each
  const int i0 = w * 50;
  loadK(i0);
  loadV(i0);

  for (int it = 0; it < 50; ++it) {
    const int i2 = i0 + it;
    const int inext = (it == 49) ? i0 : i2 + 1;

    // ---- both strips' S-MFMAs (4 independent chains), Q from registers
    f32x4 a0[2], a1[2];
    #pragma unroll
    for (int s = 0; s < 2; ++s) {
      f32x4 t0 = zero4, t1 = zero4;
      #pragma unroll
      for (int c0 = 0; c0 < 2; ++c0) {
        t0 = __builtin_amdgcn_mfma_f32_16x16x32_bf16(kfh[0][c0], qfh[s][c0], t0, 0, 0, 0);
        t0 = __builtin_amdgcn_mfma_f32_16x16x32_bf16(kfh[0][c0], qfl[s][c0], t0, 0, 0, 0);
        t0 = __builtin_amdgcn_mfma_f32_16x16x32_bf16(kfl[0][c0], qfh[s][c0], t0, 0, 0, 0);
        t1 = __builtin_amdgcn_mfma_f32_16x16x32_bf16(kfh[1][c0], qfh[s][c0], t1, 0, 0, 0);
        t1 = __builtin_amdgcn_mfma_f32_16x16x32_bf16(kfh[1][c0], qfl[s][c0], t1, 0, 0, 0);
        t1 = __builtin_amdgcn_mfma_f32_16x16x32_bf16(kfl[1][c0], qfh[s][c0], t1, 0, 0, 0);
      }
      a0[s] = t0; a1[s] = t1;
    }

    SCHED_FENCE();
    loadK(inext);
    SCHED_FENCE();

    // ---- softmax: exp2 + packed RNE, P hi-only
    #pragma unroll
    for (int s = 0; s < 2; ++s) {
      float p0 = EXP2(a0[s][0] - SHIFT2), p1 = EXP2(a0[s][1] - SHIFT2);
      float p2 = EXP2(a0[s][2] - SHIFT2), p3 = EXP2(a0[s][3] - SHIFT2);
      float p4 = EXP2(a1[s][0] - SHIFT2), p5 = EXP2(a1[s][1] - SHIFT2);
      float p6 = EXP2(a1[s][2] - SHIFT2), p7 = EXP2(a1[s][3] - SHIFT2);
      union { unsigned u[2]; short4 s4; } ua, ub;
      ua.u[0] = pk2(p0, p1); ua.u[1] = pk2(p2, p3);
      ub.u[0] = pk2(p4, p5); ub.u[1] = pk2(p6, p7);
      const int gbase = (s * 4 + (qq >> 1)) * 16 + l16;
      *(short4*)(P + (gbase * 8 + 4 * (qq & 1))) = ua.s4;
      *(short4*)(P + ((gbase + 32) * 8 + 4 * (qq & 1))) = ub.s4;
    }

    bf16x8 pf[2];
    #pragma unroll
    for (int s = 0; s < 2; ++s)
      pf[s] = *(const bf16x8*)(P + (((s * 4 + qq) * 16 + l16) * 8));

    // ---- O^T += Vh * P^T ; l += 1 * P
    #pragma unroll
    for (int ct = 0; ct < 4; ++ct)
      #pragma unroll
      for (int s = 0; s < 2; ++s)
        oacc[ct][s] = __builtin_amdgcn_mfma_f32_16x16x32_bf16(vfh[ct], pf[s], oacc[ct][s], 0, 0, 0);
    #pragma unroll
    for (int s = 0; s < 2; ++s)
      lacc[s] = __builtin_amdgcn_mfma_f32_16x16x32_bf16(onesA, pf[s], lacc[s], 0, 0, 0);

    SCHED_FENCE();
    loadV(inext);
    SCHED_FENCE();
  }

  // ---------------- in-block combine across the 4 m-quarters ----------------
  if (qq == 0) {
    #pragma unroll
    for (int s = 0; s < 2; ++s) LST[w * 32 + s * 16 + l16] = lacc[s][0];
  }
  __syncthreads();    // loop done; P region free for OC

  #pragma unroll
  for (int wp = 0; wp < 4; ++wp) {
    if (w == wp) {
      #pragma unroll
      for (int ct = 0; ct < 4; ++ct)
        #pragma unroll
        for (int s = 0; s < 2; ++s)
          #pragma unroll
          for (int r = 0; r < 4; ++r) {
            const int c = 16 * ct + 4 * qq + r;
            const int idx = c * 33 + 16 * s + l16;
            if (wp == 0) OC[idx] = oacc[ct][s][r];
            else         OC[idx] += oacc[ct][s][r];
          }
    }
    __syncthreads();
  }

  // final scale + coalesced store: 256 threads, 8 channels each (32 rows)
  {
    const int r  = tid & 31;
    const int cg = tid >> 5;          // 0..7
    float lsum = 0.f;
    #pragma unroll
    for (int w2 = 0; w2 < 4; ++w2)
      lsum += LST[w2 * 32 + (r >> 4) * 16 + (r & 15)];
    const float inv = 1.0f / lsum;
    #pragma unroll
    for (int u = 0; u < 8; ++u) {
      const int c = cg * 8 + u;
      ob[(size_t)c * NPIX + rb + r] = OC[c * 33 + r] * inv;
    }
  }
}

extern "C" void kernel_launch(void* const* d_in, const int* in_sizes, int n_in,
                              void* d_out, int out_size, void* d_ws, size_t ws_size,
                              hipStream_t stream) {
  const float* query  = (const float*)d_in[0];
  const float* keys   = (const float*)d_in[1];
  const float* values = (const float*)d_in[2];
  const float* Wq     = (const float*)d_in[3];
  const float* bq     = (const float*)d_in[4];
  short* ws = (short*)d_ws;           // 5*SZ*2 = 16.4 MB
  prep<<<dim3(1000), dim3(256), 0, stream>>>(query, keys, values, Wq, bq, ws);
  attn_main<<<dim3(800), dim3(256), 0, stream>>>(ws, (float*)d_out);
}

// Round 15
// 161.023 us; speedup vs baseline: 1.2963x; 1.1524x over previous
//
#include <hip/hip_runtime.h>
#include <hip/hip_bf16.h>

// CostAttention on MI355X — round 28: 2-term S (drop K-lo), best-known config.
// R27 post-mortem: Q-in-regs regressed AGAIN (+4us, no spill) — confirmed:
// loop-invariant LDS reads < register residency here. Reverted.
// 7 structural variants all pin attn at ~105us; MfmaUtil+VALUBusy ~70%,
// ~30% dependency-wait. Only lever left: less work.
// This round: S = Kh*(Qh+Ql) only — drop the Kl*Qh term (3->2 MFMA terms).
// Error analysis: dropped term sigma ~0.0013 in log2 domain (~0.1% P), half
// of existing P-RNE error; absmax predicted 4-7e-4 vs threshold 1.318e-3
// (current 2.44e-4, 5.4x headroom). TRIPWIRE: absmax>1.318e-3 -> restore.
// Cuts: S-MFMA 48->32/iter (-24% MFMA work), kfl VMEM loads deleted (K
// traffic -50%), prepK skips Kl compute+store. attn = R14-exact structure
// (session-best 105.0); prep = R22 combined (177.0 total measured).
//
// ws layout: shorts [Qh][Ql][Kh][Kl(unused)][Vh], each SZ = 1,638,400 shorts.
//   Q/K chunk  ((b*400+mi)*2+c0)*512 + lane*8 : elem [r=16mi+l16][c=32c0+8qq+j]
//   V   chunk  (((b*100+i64)*8)+ct*2+mh)*512 + lane*8 : elem [c=16ct+l16][m=64i64+32mh+8qq+j]

#define NPIX 6400
#define SZ 1638400
#define SHIFT2 11.541560327111707f   // 8 * log2(e)

typedef float f32x4 __attribute__((ext_vector_type(4)));
typedef short bf16x8 __attribute__((ext_vector_type(8)));

#if defined(__has_builtin)
#if __has_builtin(__builtin_amdgcn_sched_barrier)
#define SCHED_FENCE() __builtin_amdgcn_sched_barrier(0)
#endif
#if __has_builtin(__builtin_amdgcn_exp2f)
#define EXP2(x) __builtin_amdgcn_exp2f(x)
#endif
#endif
#ifndef SCHED_FENCE
#define SCHED_FENCE()
#endif
#ifndef EXP2
#define EXP2(x) exp2f(x)
#endif

__device__ __forceinline__ void split2(float x, short& h, short& l) {
  unsigned xb = __float_as_uint(x);
  h = (short)(xb >> 16);
  float r = x - __uint_as_float(xb & 0xffff0000u);
  l = (short)(__float_as_uint(r) >> 16);
}

__device__ __forceinline__ short rne_bf16(float x) {
  unsigned u = __float_as_uint(x);
  return (short)((u + 0x7fffu + ((u >> 16) & 1u)) >> 16);
}

__device__ __forceinline__ unsigned pk2(float a, float b) {
  __hip_bfloat162 t = __float22bfloat162_rn(make_float2(a, b));
  unsigned r;
  __builtin_memcpy(&r, &t, 4);
  return r;
}

// ---------------- prep (combined): K trunc-hi only | Q proj+split | V RNE ---
// grid 1000: [0,400) K (b,m-tile) | [400,800) Q-proj (b,r-tile) | [800,1000) V
__global__ __launch_bounds__(256, 4) void prep(
    const float* __restrict__ query, const float* __restrict__ keys,
    const float* __restrict__ values, const float* __restrict__ Wq,
    const float* __restrict__ bq, short* __restrict__ ws)
{
  const int tid = threadIdx.x;
  const int w = tid >> 6;
  const int lane = tid & 63, l16 = lane & 15, qq = lane >> 4;
  short* Qh = ws;          short* Ql = ws + SZ;
  short* Kh = ws + 2 * SZ;
  short* Vh = ws + 4 * SZ;
  const int x = blockIdx.x;

  __shared__ float T[64 * 65];   // 16.6 KB; Q phase reuses it for outputs

  if (x < 400) {                      // ---- K: trunc-hi bf16 only (2-term S)
    const int b = x / 100, t64 = x % 100;
    const int m0 = t64 * 64;
    const float* kb = keys + (size_t)b * 64 * NPIX;
    {
      const int ch = tid >> 2, ml = (tid & 3) * 4;
      const float* src = kb + (size_t)ch * NPIX + m0 + ml;
      #pragma unroll
      for (int u = 0; u < 4; ++u)
        *(float4*)&T[ch * 65 + ml + 16 * u] = *(const float4*)(src + 16 * u);
    }
    __syncthreads();
    const int mi = t64 * 4 + w;
    #pragma unroll
    for (int c0 = 0; c0 < 2; ++c0) {
      float t[8];
      #pragma unroll
      for (int j = 0; j < 8; ++j)
        t[j] = T[(32 * c0 + 8 * qq + j) * 65 + 16 * w + l16];
      bf16x8 h8;
      #pragma unroll
      for (int j = 0; j < 8; ++j)
        h8[j] = (short)(__float_as_uint(t[j]) >> 16);   // trunc hi
      const int off = ((b * 400 + mi) * 2 + c0) * 512 + lane * 8;
      *(bf16x8*)(Kh + off) = h8;
    }
  } else if (x < 800) {               // ---- Q projection + trunc hi/lo split
    const int y = x - 400;
    const int b = y / 100, t64 = y % 100;
    const int r0 = t64 * 64;
    const float* qb = query + (size_t)b * 64 * NPIX;
    {
      const int ch = tid >> 2, ml = (tid & 3) * 4;
      const float* src = qb + (size_t)ch * NPIX + r0 + ml;
      #pragma unroll
      for (int u = 0; u < 4; ++u)
        *(float4*)&T[ch * 65 + ml + 16 * u] = *(const float4*)(src + 16 * u);
    }
    __syncthreads();

    {
      float xv[64];
      #pragma unroll
      for (int cin = 0; cin < 64; ++cin)
        xv[cin] = T[cin * 65 + lane];
      __syncthreads();   // all xv reads done before T is overwritten

      #pragma unroll 4
      for (int c16 = 0; c16 < 16; ++c16) {
        const int co = __builtin_amdgcn_readfirstlane(16 * w + c16);
        const float* row = Wq + co * 64;
        float a = 0.f;
        #pragma unroll
        for (int cin = 0; cin < 64; ++cin)
          a += row[cin] * xv[cin];
        // scale = (1/8)*log2(e): S in log2 domain -> raw exp2 in main
        T[co * 65 + lane] = (a + bq[co]) * 0.18033688011112042f;
      }
    }
    __syncthreads();

    const int mi = t64 * 4 + w;
    #pragma unroll
    for (int c0 = 0; c0 < 2; ++c0) {
      float t[8];
      #pragma unroll
      for (int j = 0; j < 8; ++j)
        t[j] = T[(32 * c0 + 8 * qq + j) * 65 + 16 * w + l16];
      bf16x8 h8, l8;
      #pragma unroll
      for (int j = 0; j < 8; ++j) { short h, l; split2(t[j], h, l); h8[j] = h; l8[j] = l; }
      const int off = ((b * 400 + mi) * 2 + c0) * 512 + lane * 8;
      *(bf16x8*)(Qh + off) = h8;
      *(bf16x8*)(Ql + off) = l8;
    }
  } else {                            // ---- V: RNE bf16, hi only
    const int gw = (x - 800) * 4 + w;
    const int b = gw / 200, rest = gw % 200;
    const int i = rest / 2, half = rest % 2;
    const float* vb = values + (size_t)b * 64 * NPIX;
    #pragma unroll
    for (int cc = 0; cc < 2; ++cc) {
      const int ct = 2 * half + cc;
      #pragma unroll
      for (int mh = 0; mh < 2; ++mh) {
        const float* vp = vb + (size_t)(16 * ct + l16) * NPIX + 64 * i + 32 * mh + 8 * qq;
        const float4 a  = *(const float4*)vp;
        const float4 b4 = *(const float4*)(vp + 4);
        const float t[8] = {a.x, a.y, a.z, a.w, b4.x, b4.y, b4.z, b4.w};
        bf16x8 h8;
        #pragma unroll
        for (int j = 0; j < 8; ++j) h8[j] = rne_bf16(t[j]);
        const int off = (((b * 100 + i) * 8) + ct * 2 + mh) * 512 + lane * 8;
        *(bf16x8*)(Vh + off) = h8;
      }
    }
  }
}

// ---------------- main: 400 blocks x 512 thr; 8-wave in-block m-split -------
// R14-exact structure (session-best 105.0), minus the K-lo term:
// S = Kh*Qh + Kh*Ql (2-term). loadK fetches kfh only.
__global__ __launch_bounds__(512, 1) void attn_main(
    const short* __restrict__ ws, float* __restrict__ out)
{
  const int tid  = threadIdx.x;
  const int w    = tid >> 6;          // wave 0..7 = m-eighth
  const int lane = tid & 63;
  const int l16  = lane & 15, qq = lane >> 4;
  const int x = blockIdx.x;
  const int b      = x & 3;           // batch -> XCDs {b, b+4}; KV < L2
  const int rowjob = x >> 2;          // 0..99
  const int rb     = rowjob * 64;

  const short* Qh = ws;
  const short* Kh = ws + 2 * SZ;
  const short* Vh = ws + 4 * SZ;
  float* ob = out + (size_t)b * 64 * NPIX;

  // LDS: loop — per-wave P (8 x 4 KB) + shared Q-lo (8 KB) = 40 KB;
  // combine — OC [64][65] f32 (16640 B, aliases P) + LST (2 KB at 40960).
  __shared__ char smem[43008];
  short* P   = ((short*)smem) + (w << 11);   // wave-private 2048 shorts
  short* QL  = ((short*)smem) + 16384;       // shared Q-lo frags (8 KB)
  float* OC  = (float*)smem;
  float* LST = (float*)(smem + 40960);       // [8 waves][4 strips][16]

  bf16x8 qfh[4][2];
  {
    const short* qp = Qh + (size_t)((b * 400 + rowjob * 4) * 2) * 512 + lane * 8;
    #pragma unroll
    for (int s = 0; s < 4; ++s)
      #pragma unroll
      for (int c0 = 0; c0 < 2; ++c0) {
        qfh[s][c0] = *(const bf16x8*)(qp + (s * 2 + c0) * 512);
        *(bf16x8*)(QL + ((s * 2 + c0) * 64 + lane) * 8) =
            *(const bf16x8*)(qp + SZ + (s * 2 + c0) * 512);   // 8x redundant, benign
      }
  }
  __syncthreads();

  f32x4 zero4 = {0.f, 0.f, 0.f, 0.f};
  f32x4 oacc[4][4];
  f32x4 lacc[4];
  #pragma unroll
  for (int ct = 0; ct < 4; ++ct)
    #pragma unroll
    for (int s = 0; s < 4; ++s) oacc[ct][s] = zero4;
  #pragma unroll
  for (int s = 0; s < 4; ++s) lacc[s] = zero4;

  bf16x8 onesA;
  #pragma unroll
  for (int j = 0; j < 8; ++j) onesA[j] = (short)0x3F80;

  bf16x8 kfh[2][2];
  bf16x8 vfh[4];

  auto loadK = [&](int i2) {
    const short* kp = Kh + (size_t)((b * 400 + 2 * i2) * 2) * 512 + lane * 8;
    #pragma unroll
    for (int mt = 0; mt < 2; ++mt)
      #pragma unroll
      for (int c0 = 0; c0 < 2; ++c0)
        kfh[mt][c0] = *(const bf16x8*)(kp + (mt * 2 + c0) * 512);
  };
  auto loadV = [&](int i2) {
    const short* vp = Vh + (size_t)((b * 100 + (i2 >> 1)) * 8) * 512 + lane * 8;
    #pragma unroll
    for (int ct = 0; ct < 4; ++ct)
      vfh[ct] = *(const bf16x8*)(vp + (ct * 2 + (i2 & 1)) * 512);
  };

  // wave w owns m-chunks [25w, 25w+25) of 32 m each
  const int i0 = w * 25;
  loadK(i0);
  loadV(i0);

  for (int it = 0; it < 25; ++it) {
    const int i2 = i0 + it;
    const int inext = (it == 24) ? i0 : i2 + 1;

    // ---- all strips' S-MFMAs (2-term: Kh*Qh + Kh*Ql)
    f32x4 a0[4], a1[4];
    #pragma unroll
    for (int s = 0; s < 4; ++s) {
      f32x4 t0 = zero4, t1 = zero4;
      #pragma unroll
      for (int c0 = 0; c0 < 2; ++c0) {
        const bf16x8 ql = *(const bf16x8*)(QL + ((s * 2 + c0) * 64 + lane) * 8);
        t0 = __builtin_amdgcn_mfma_f32_16x16x32_bf16(kfh[0][c0], qfh[s][c0], t0, 0, 0, 0);
        t0 = __builtin_amdgcn_mfma_f32_16x16x32_bf16(kfh[0][c0], ql,         t0, 0, 0, 0);
        t1 = __builtin_amdgcn_mfma_f32_16x16x32_bf16(kfh[1][c0], qfh[s][c0], t1, 0, 0, 0);
        t1 = __builtin_amdgcn_mfma_f32_16x16x32_bf16(kfh[1][c0], ql,         t1, 0, 0, 0);
      }
      a0[s] = t0; a1[s] = t1;
    }

    SCHED_FENCE();
    loadK(inext);
    SCHED_FENCE();

    // ---- softmax: exp2 + packed RNE, P hi-only
    #pragma unroll
    for (int s = 0; s < 4; ++s) {
      float p0 = EXP2(a0[s][0] - SHIFT2), p1 = EXP2(a0[s][1] - SHIFT2);
      float p2 = EXP2(a0[s][2] - SHIFT2), p3 = EXP2(a0[s][3] - SHIFT2);
      float p4 = EXP2(a1[s][0] - SHIFT2), p5 = EXP2(a1[s][1] - SHIFT2);
      float p6 = EXP2(a1[s][2] - SHIFT2), p7 = EXP2(a1[s][3] - SHIFT2);
      union { unsigned u[2]; short4 s4; } ua, ub;
      ua.u[0] = pk2(p0, p1); ua.u[1] = pk2(p2, p3);
      ub.u[0] = pk2(p4, p5); ub.u[1] = pk2(p6, p7);
      const int gbase = (s * 4 + (qq >> 1)) * 16 + l16;
      *(short4*)(P + (gbase * 8 + 4 * (qq & 1))) = ua.s4;
      *(short4*)(P + ((gbase + 32) * 8 + 4 * (qq & 1))) = ub.s4;
    }

    bf16x8 pf[4];
    #pragma unroll
    for (int s = 0; s < 4; ++s)
      pf[s] = *(const bf16x8*)(P + (((s * 4 + qq) * 16 + l16) * 8));

    // ---- O^T += Vh * P^T ; l += 1 * P
    #pragma unroll
    for (int ct = 0; ct < 4; ++ct)
      #pragma unroll
      for (int s = 0; s < 4; ++s)
        oacc[ct][s] = __builtin_amdgcn_mfma_f32_16x16x32_bf16(vfh[ct], pf[s], oacc[ct][s], 0, 0, 0);
    #pragma unroll
    for (int s = 0; s < 4; ++s)
      lacc[s] = __builtin_amdgcn_mfma_f32_16x16x32_bf16(onesA, pf[s], lacc[s], 0, 0, 0);

    SCHED_FENCE();
    loadV(inext);
    SCHED_FENCE();
  }

  // ---------------- in-block combine across the 8 m-eighths -----------------
  if (qq == 0) {
    #pragma unroll
    for (int s = 0; s < 4; ++s) LST[w * 64 + s * 16 + l16] = lacc[s][0];
  }
  __syncthreads();    // loop done; P region free for OC

  #pragma unroll
  for (int wp = 0; wp < 8; ++wp) {
    if (w == wp) {
      #pragma unroll
      for (int ct = 0; ct < 4; ++ct)
        #pragma unroll
        for (int s = 0; s < 4; ++s)
          #pragma unroll
          for (int r = 0; r < 4; ++r) {
            const int c = 16 * ct + 4 * qq + r;
            const int idx = c * 65 + 16 * s + l16;
            if (wp == 0) OC[idx] = oacc[ct][s][r];
            else         OC[idx] += oacc[ct][s][r];
          }
    }
    __syncthreads();
  }

  // final scale + coalesced store: 512 threads, 8 channels each
  {
    const int r  = tid & 63;
    const int cg = tid >> 6;          // 0..7
    float lsum = 0.f;
    #pragma unroll
    for (int w2 = 0; w2 < 8; ++w2)
      lsum += LST[w2 * 64 + (r >> 4) * 16 + (r & 15)];
    const float inv = 1.0f / lsum;
    #pragma unroll
    for (int u = 0; u < 8; ++u) {
      const int c = cg * 8 + u;
      ob[(size_t)c * NPIX + rb + r] = OC[c * 65 + r] * inv;
    }
  }
}

extern "C" void kernel_launch(void* const* d_in, const int* in_sizes, int n_in,
                              void* d_out, int out_size, void* d_ws, size_t ws_size,
                              hipStream_t stream) {
  const float* query  = (const float*)d_in[0];
  const float* keys   = (const float*)d_in[1];
  const float* values = (const float*)d_in[2];
  const float* Wq     = (const float*)d_in[3];
  const float* bq     = (const float*)d_in[4];
  short* ws = (short*)d_ws;           // 5*SZ*2 = 16.4 MB
  prep<<<dim3(1000), dim3(256), 0, stream>>>(query, keys, values, Wq, bq, ws);
  attn_main<<<dim3(400), dim3(512), 0, stream>>>(ws, (float*)d_out);
}

// Round 16
// 150.766 us; speedup vs baseline: 1.3845x; 1.0680x over previous
//
#include <hip/hip_runtime.h>
#include <hip/hip_bf16.h>

// CostAttention on MI355X — round 29: 1-term S, RNE-rounded K and Q.
// R28 post-mortem: 2-term S WON (attn 105->90, total 161.0 best, absmax
// 4.88e-4 = predicted band). Work-cut is the only lever that moves attn
// (7 structural variants: 0; one work cut: -15us). Push it to the endpoint:
// store K and Q as RNE bf16 (+-0.5ulp unbiased vs trunc's 1ulp biased) and
// compute S = mfma(Kr,Qr) single-term. Error: Q-RNE sigma~0.0028 log2-domain
// (~0.2% P) atop existing ~0.2% K + 0.4% P-RNE -> absmax predicted 7-10e-4
// vs threshold 1.318e-3. TRIPWIRE: fail -> revert to R28 (161.0 known-good).
// Cuts: S-MFMA 32->16/iter (52->36 total, -31%); QL staging + 8 ds_reads/iter
// deleted (loop LDS = P round-trip only); prepQ single array; initial block
// barrier removed. attn structure otherwise R14/R28-exact; prep R22 combined.
//
// ws layout: shorts [Qr][unused][Kr][unused][Vh], each SZ = 1,638,400 shorts.
//   Q/K chunk  ((b*400+mi)*2+c0)*512 + lane*8 : elem [r=16mi+l16][c=32c0+8qq+j]
//   V   chunk  (((b*100+i64)*8)+ct*2+mh)*512 + lane*8 : elem [c=16ct+l16][m=64i64+32mh+8qq+j]

#define NPIX 6400
#define SZ 1638400
#define SHIFT2 11.541560327111707f   // 8 * log2(e)

typedef float f32x4 __attribute__((ext_vector_type(4)));
typedef short bf16x8 __attribute__((ext_vector_type(8)));

#if defined(__has_builtin)
#if __has_builtin(__builtin_amdgcn_sched_barrier)
#define SCHED_FENCE() __builtin_amdgcn_sched_barrier(0)
#endif
#if __has_builtin(__builtin_amdgcn_exp2f)
#define EXP2(x) __builtin_amdgcn_exp2f(x)
#endif
#endif
#ifndef SCHED_FENCE
#define SCHED_FENCE()
#endif
#ifndef EXP2
#define EXP2(x) exp2f(x)
#endif

__device__ __forceinline__ short rne_bf16(float x) {
  unsigned u = __float_as_uint(x);
  return (short)((u + 0x7fffu + ((u >> 16) & 1u)) >> 16);
}

__device__ __forceinline__ unsigned pk2(float a, float b) {
  __hip_bfloat162 t = __float22bfloat162_rn(make_float2(a, b));
  unsigned r;
  __builtin_memcpy(&r, &t, 4);
  return r;
}

// ---------------- prep (combined): K RNE | Q proj+RNE | V RNE ---------------
// grid 1000: [0,400) K (b,m-tile) | [400,800) Q-proj (b,r-tile) | [800,1000) V
__global__ __launch_bounds__(256, 4) void prep(
    const float* __restrict__ query, const float* __restrict__ keys,
    const float* __restrict__ values, const float* __restrict__ Wq,
    const float* __restrict__ bq, short* __restrict__ ws)
{
  const int tid = threadIdx.x;
  const int w = tid >> 6;
  const int lane = tid & 63, l16 = lane & 15, qq = lane >> 4;
  short* Qr = ws;
  short* Kr = ws + 2 * SZ;
  short* Vh = ws + 4 * SZ;
  const int x = blockIdx.x;

  __shared__ float T[64 * 65];   // 16.6 KB; Q phase reuses it for outputs

  if (x < 400) {                      // ---- K: RNE bf16 (1-term S)
    const int b = x / 100, t64 = x % 100;
    const int m0 = t64 * 64;
    const float* kb = keys + (size_t)b * 64 * NPIX;
    {
      const int ch = tid >> 2, ml = (tid & 3) * 4;
      const float* src = kb + (size_t)ch * NPIX + m0 + ml;
      #pragma unroll
      for (int u = 0; u < 4; ++u)
        *(float4*)&T[ch * 65 + ml + 16 * u] = *(const float4*)(src + 16 * u);
    }
    __syncthreads();
    const int mi = t64 * 4 + w;
    #pragma unroll
    for (int c0 = 0; c0 < 2; ++c0) {
      float t[8];
      #pragma unroll
      for (int j = 0; j < 8; ++j)
        t[j] = T[(32 * c0 + 8 * qq + j) * 65 + 16 * w + l16];
      bf16x8 h8;
      #pragma unroll
      for (int j = 0; j < 8; ++j) h8[j] = rne_bf16(t[j]);
      const int off = ((b * 400 + mi) * 2 + c0) * 512 + lane * 8;
      *(bf16x8*)(Kr + off) = h8;
    }
  } else if (x < 800) {               // ---- Q projection + RNE bf16
    const int y = x - 400;
    const int b = y / 100, t64 = y % 100;
    const int r0 = t64 * 64;
    const float* qb = query + (size_t)b * 64 * NPIX;
    {
      const int ch = tid >> 2, ml = (tid & 3) * 4;
      const float* src = qb + (size_t)ch * NPIX + r0 + ml;
      #pragma unroll
      for (int u = 0; u < 4; ++u)
        *(float4*)&T[ch * 65 + ml + 16 * u] = *(const float4*)(src + 16 * u);
    }
    __syncthreads();

    {
      float xv[64];
      #pragma unroll
      for (int cin = 0; cin < 64; ++cin)
        xv[cin] = T[cin * 65 + lane];
      __syncthreads();   // all xv reads done before T is overwritten

      #pragma unroll 4
      for (int c16 = 0; c16 < 16; ++c16) {
        const int co = __builtin_amdgcn_readfirstlane(16 * w + c16);
        const float* row = Wq + co * 64;
        float a = 0.f;
        #pragma unroll
        for (int cin = 0; cin < 64; ++cin)
          a += row[cin] * xv[cin];
        // scale = (1/8)*log2(e): S in log2 domain -> raw exp2 in main
        T[co * 65 + lane] = (a + bq[co]) * 0.18033688011112042f;
      }
    }
    __syncthreads();

    const int mi = t64 * 4 + w;
    #pragma unroll
    for (int c0 = 0; c0 < 2; ++c0) {
      float t[8];
      #pragma unroll
      for (int j = 0; j < 8; ++j)
        t[j] = T[(32 * c0 + 8 * qq + j) * 65 + 16 * w + l16];
      bf16x8 h8;
      #pragma unroll
      for (int j = 0; j < 8; ++j) h8[j] = rne_bf16(t[j]);
      const int off = ((b * 400 + mi) * 2 + c0) * 512 + lane * 8;
      *(bf16x8*)(Qr + off) = h8;
    }
  } else {                            // ---- V: RNE bf16, hi only
    const int gw = (x - 800) * 4 + w;
    const int b = gw / 200, rest = gw % 200;
    const int i = rest / 2, half = rest % 2;
    const float* vb = values + (size_t)b * 64 * NPIX;
    #pragma unroll
    for (int cc = 0; cc < 2; ++cc) {
      const int ct = 2 * half + cc;
      #pragma unroll
      for (int mh = 0; mh < 2; ++mh) {
        const float* vp = vb + (size_t)(16 * ct + l16) * NPIX + 64 * i + 32 * mh + 8 * qq;
        const float4 a  = *(const float4*)vp;
        const float4 b4 = *(const float4*)(vp + 4);
        const float t[8] = {a.x, a.y, a.z, a.w, b4.x, b4.y, b4.z, b4.w};
        bf16x8 h8;
        #pragma unroll
        for (int j = 0; j < 8; ++j) h8[j] = rne_bf16(t[j]);
        const int off = (((b * 100 + i) * 8) + ct * 2 + mh) * 512 + lane * 8;
        *(bf16x8*)(Vh + off) = h8;
      }
    }
  }
}

// ---------------- main: 400 blocks x 512 thr; 8-wave in-block m-split -------
// R14/R28-exact structure, 1-term S: S = Kr*Qr. 36 MFMA/iter (16 S + 16 PV
// + 4 l). Loop LDS = P round-trip only. No QL staging, no initial barrier.
// LDS: P (8 x 4 KB) = 32768 | LST [8][64] f32 = 2048 @ 32768 -> smem 34816.
// OC [64][65] f32 (16640 B) aliases P after the loop.
__global__ __launch_bounds__(512, 1) void attn_main(
    const short* __restrict__ ws, float* __restrict__ out)
{
  const int tid  = threadIdx.x;
  const int w    = tid >> 6;          // wave 0..7 = m-eighth
  const int lane = tid & 63;
  const int l16  = lane & 15, qq = lane >> 4;
  const int x = blockIdx.x;
  const int b      = x & 3;           // batch -> XCDs {b, b+4}; KV < L2
  const int rowjob = x >> 2;          // 0..99
  const int rb     = rowjob * 64;

  const short* Qr = ws;
  const short* Kr = ws + 2 * SZ;
  const short* Vh = ws + 4 * SZ;
  float* ob = out + (size_t)b * 64 * NPIX;

  __shared__ char smem[34816];
  short* P   = ((short*)smem) + (w << 11);   // wave-private 2048 shorts
  float* OC  = (float*)smem;
  float* LST = (float*)(smem + 32768);       // [8 waves][4 strips][16] = 2 KB

  // Q frags (RNE bf16), loop-invariant, in registers
  bf16x8 qf[4][2];
  {
    const short* qp = Qr + (size_t)((b * 400 + rowjob * 4) * 2) * 512 + lane * 8;
    #pragma unroll
    for (int s = 0; s < 4; ++s)
      #pragma unroll
      for (int c0 = 0; c0 < 2; ++c0)
        qf[s][c0] = *(const bf16x8*)(qp + (s * 2 + c0) * 512);
  }

  f32x4 zero4 = {0.f, 0.f, 0.f, 0.f};
  f32x4 oacc[4][4];
  f32x4 lacc[4];
  #pragma unroll
  for (int ct = 0; ct < 4; ++ct)
    #pragma unroll
    for (int s = 0; s < 4; ++s) oacc[ct][s] = zero4;
  #pragma unroll
  for (int s = 0; s < 4; ++s) lacc[s] = zero4;

  bf16x8 onesA;
  #pragma unroll
  for (int j = 0; j < 8; ++j) onesA[j] = (short)0x3F80;

  bf16x8 kf[2][2];
  bf16x8 vfh[4];

  auto loadK = [&](int i2) {
    const short* kp = Kr + (size_t)((b * 400 + 2 * i2) * 2) * 512 + lane * 8;
    #pragma unroll
    for (int mt = 0; mt < 2; ++mt)
      #pragma unroll
      for (int c0 = 0; c0 < 2; ++c0)
        kf[mt][c0] = *(const bf16x8*)(kp + (mt * 2 + c0) * 512);
  };
  auto loadV = [&](int i2) {
    const short* vp = Vh + (size_t)((b * 100 + (i2 >> 1)) * 8) * 512 + lane * 8;
    #pragma unroll
    for (int ct = 0; ct < 4; ++ct)
      vfh[ct] = *(const bf16x8*)(vp + (ct * 2 + (i2 & 1)) * 512);
  };

  // wave w owns m-chunks [25w, 25w+25) of 32 m each
  const int i0 = w * 25;
  loadK(i0);
  loadV(i0);

  for (int it = 0; it < 25; ++it) {
    const int i2 = i0 + it;
    const int inext = (it == 24) ? i0 : i2 + 1;

    // ---- all strips' S-MFMAs (1-term: Kr*Qr)
    f32x4 a0[4], a1[4];
    #pragma unroll
    for (int s = 0; s < 4; ++s) {
      f32x4 t0 = zero4, t1 = zero4;
      #pragma unroll
      for (int c0 = 0; c0 < 2; ++c0) {
        t0 = __builtin_amdgcn_mfma_f32_16x16x32_bf16(kf[0][c0], qf[s][c0], t0, 0, 0, 0);
        t1 = __builtin_amdgcn_mfma_f32_16x16x32_bf16(kf[1][c0], qf[s][c0], t1, 0, 0, 0);
      }
      a0[s] = t0; a1[s] = t1;
    }

    SCHED_FENCE();
    loadK(inext);
    SCHED_FENCE();

    // ---- softmax: exp2 + packed RNE, P hi-only
    #pragma unroll
    for (int s = 0; s < 4; ++s) {
      float p0 = EXP2(a0[s][0] - SHIFT2), p1 = EXP2(a0[s][1] - SHIFT2);
      float p2 = EXP2(a0[s][2] - SHIFT2), p3 = EXP2(a0[s][3] - SHIFT2);
      float p4 = EXP2(a1[s][0] - SHIFT2), p5 = EXP2(a1[s][1] - SHIFT2);
      float p6 = EXP2(a1[s][2] - SHIFT2), p7 = EXP2(a1[s][3] - SHIFT2);
      union { unsigned u[2]; short4 s4; } ua, ub;
      ua.u[0] = pk2(p0, p1); ua.u[1] = pk2(p2, p3);
      ub.u[0] = pk2(p4, p5); ub.u[1] = pk2(p6, p7);
      const int gbase = (s * 4 + (qq >> 1)) * 16 + l16;
      *(short4*)(P + (gbase * 8 + 4 * (qq & 1))) = ua.s4;
      *(short4*)(P + ((gbase + 32) * 8 + 4 * (qq & 1))) = ub.s4;
    }

    bf16x8 pf[4];
    #pragma unroll
    for (int s = 0; s < 4; ++s)
      pf[s] = *(const bf16x8*)(P + (((s * 4 + qq) * 16 + l16) * 8));

    // ---- O^T += Vh * P^T ; l += 1 * P
    #pragma unroll
    for (int ct = 0; ct < 4; ++ct)
      #pragma unroll
      for (int s = 0; s < 4; ++s)
        oacc[ct][s] = __builtin_amdgcn_mfma_f32_16x16x32_bf16(vfh[ct], pf[s], oacc[ct][s], 0, 0, 0);
    #pragma unroll
    for (int s = 0; s < 4; ++s)
      lacc[s] = __builtin_amdgcn_mfma_f32_16x16x32_bf16(onesA, pf[s], lacc[s], 0, 0, 0);

    SCHED_FENCE();
    loadV(inext);
    SCHED_FENCE();
  }

  // ---------------- in-block combine across the 8 m-eighths -----------------
  if (qq == 0) {
    #pragma unroll
    for (int s = 0; s < 4; ++s) LST[w * 64 + s * 16 + l16] = lacc[s][0];
  }
  __syncthreads();    // loop done; P region free for OC

  #pragma unroll
  for (int wp = 0; wp < 8; ++wp) {
    if (w == wp) {
      #pragma unroll
      for (int ct = 0; ct < 4; ++ct)
        #pragma unroll
        for (int s = 0; s < 4; ++s)
          #pragma unroll
          for (int r = 0; r < 4; ++r) {
            const int c = 16 * ct + 4 * qq + r;
            const int idx = c * 65 + 16 * s + l16;
            if (wp == 0) OC[idx] = oacc[ct][s][r];
            else         OC[idx] += oacc[ct][s][r];
          }
    }
    __syncthreads();
  }

  // final scale + coalesced store: 512 threads, 8 channels each
  {
    const int r  = tid & 63;
    const int cg = tid >> 6;          // 0..7
    float lsum = 0.f;
    #pragma unroll
    for (int w2 = 0; w2 < 8; ++w2)
      lsum += LST[w2 * 64 + (r >> 4) * 16 + (r & 15)];
    const float inv = 1.0f / lsum;
    #pragma unroll
    for (int u = 0; u < 8; ++u) {
      const int c = cg * 8 + u;
      ob[(size_t)c * NPIX + rb + r] = OC[c * 65 + r] * inv;
    }
  }
}

extern "C" void kernel_launch(void* const* d_in, const int* in_sizes, int n_in,
                              void* d_out, int out_size, void* d_ws, size_t ws_size,
                              hipStream_t stream) {
  const float* query  = (const float*)d_in[0];
  const float* keys   = (const float*)d_in[1];
  const float* values = (const float*)d_in[2];
  const float* Wq     = (const float*)d_in[3];
  const float* bq     = (const float*)d_in[4];
  short* ws = (short*)d_ws;           // 5*SZ*2 = 16.4 MB
  prep<<<dim3(1000), dim3(256), 0, stream>>>(query, keys, values, Wq, bq, ws);
  attn_main<<<dim3(400), dim3(512), 0, stream>>>(ws, (float*)d_out);
}